// Round 24
// baseline (160.673 us; speedup 1.0000x reference)
//
#include <hip/hip_runtime.h>
#include <hip/hip_bf16.h>
#include <math.h>

#define EPS 1e-8f

typedef __attribute__((ext_vector_type(8))) short short8v;
typedef __attribute__((ext_vector_type(4))) float f32x4;

// ---------- helpers ----------
__device__ __forceinline__ unsigned fenc(float f) {
    unsigned u = __float_as_uint(f);
    return (u & 0x80000000u) ? ~u : (u | 0x80000000u);
}
__device__ __forceinline__ float fdec(unsigned e) {
    unsigned u = (e & 0x80000000u) ? (e & 0x7FFFFFFFu) : ~e;
    return __uint_as_float(u);
}
__device__ __forceinline__ unsigned short f2bf(float f) {   // RNE f32 -> bf16
    unsigned u = __float_as_uint(f);
    u += 0x7FFFu + ((u >> 16) & 1u);
    return (unsigned short)(u >> 16);
}

__device__ __forceinline__ float block_sum(float v, float* red) {
    red[threadIdx.x] = v;
    __syncthreads();
    for (int k = 128; k > 0; k >>= 1) {
        if (threadIdx.x < k) red[threadIdx.x] += red[threadIdx.x + k];
        __syncthreads();
    }
    float r = red[0];
    __syncthreads();
    return r;
}

// ---------- kernels ----------
// per-group histogram: gh[g*1024 + c]
__global__ void k_ghist(const int* tgt, int* gh, int B) {
    __shared__ int lh[1024];
    int g = blockIdx.x, t = threadIdx.x;
    lh[t] = 0; lh[t + 256] = 0; lh[t + 512] = 0; lh[t + 768] = 0;
    __syncthreads();
    int i = g * 256 + t;
    if (i < B) atomicAdd(&lh[tgt[i]], 1);
    __syncthreads();
    int* dst = gh + g * 1024;
    dst[t] = lh[t]; dst[t + 256] = lh[t + 256];
    dst[t + 512] = lh[t + 512]; dst[t + 768] = lh[t + 768];
}

// in-place exclusive scan of gh over groups (per class), totals -> counts,
// class-exclusive-scan -> offsets. One block, 1024 threads. Also inits minmax.
__global__ void k_bases(int* gh, int* counts, int* offsets, unsigned* minmax, int G, int C) {
    __shared__ int buf[1024];
    int c = threadIdx.x;
    if (c == 0) { minmax[0] = 0xFFFFFFFFu; minmax[1] = 0u; }
    int run = 0;
#pragma unroll 16
    for (int g = 0; g < G; g++) {
        int v = gh[g * 1024 + c];
        gh[g * 1024 + c] = run;
        run += v;
    }
    if (c < C) counts[c] = run;
    int v0 = (c < C) ? run : 0;
    buf[c] = v0;
    __syncthreads();
    for (int off = 1; off < 1024; off <<= 1) {
        int v = (c >= off) ? buf[c - off] : 0;
        __syncthreads();
        buf[c] += v;
        __syncthreads();
    }
    if (c < C) offsets[c] = buf[c] - v0;
}

// stable rank within group via LDS compare-count; deterministic idx
__global__ void k_rank_scatter(const int* tgt, const int* offsets, const int* gh,
                               int* idx, int B) {
    __shared__ int lt[256];
    int g = blockIdx.x, t = threadIdx.x;
    int i = g * 256 + t;
    int my = (i < B) ? tgt[i] : -1;
    lt[t] = my;
    __syncthreads();
    if (i < B) {
        int rank = 0;
        for (int j = 0; j < t; j++) rank += (lt[j] == my);
        idx[offsets[my] + gh[g * 1024 + my] + rank] = i;
    }
}

// FUSED table build: blocks [0,C) -> feature table + norms; blocks [C,2C) -> logit table.
// Hot loop: NO LDS, NO pointer-select. Indices in per-lane register (one coalesced
// load per 64-row chunk), broadcast via __shfl. Unconditional float4 loads, x4
// unroll, ascending accumulation order (deterministic).
__global__ __launch_bounds__(256) void k_tables(const float* feat, const float* finit,
                                                const float* logits, const float* linit,
                                                const int* counts, const int* offsets,
                                                const int* idx,
                                                float* ftab, float* ltab, float* norms,
                                                int C, int D, int C2) {
    __shared__ float red[256];
    int t = threadIdx.x;
    int lane = t & 63;
    if ((int)blockIdx.x < C) {
        // ---------------- feature path (W = D = 1024, all 256 lanes valid) --------
        int c = blockIdx.x;
        int n = counts[c];
        float o0, o1, o2, o3;
        if (n == 0) {
            float4 v = ((const float4*)(finit + (long)c * D))[t];
            o0 = v.x; o1 = v.y; o2 = v.z; o3 = v.w;
        } else {
            const float4* base4 = (const float4*)feat;
            int rowq = D >> 2;                      // 256 float4 per row
            int o = offsets[c];
            float4 acc = {0.f, 0.f, 0.f, 0.f};
            for (int base = 0; base < n; base += 64) {
                int m = min(64, n - base);
                int lid = idx[o + base + min(lane, m - 1)];   // per-lane register
                int m4 = m & ~3;
                int j = 0;
                for (; j < m4; j += 4) {
                    int i0 = __shfl(lid, j);
                    int i1 = __shfl(lid, j + 1);
                    int i2 = __shfl(lid, j + 2);
                    int i3 = __shfl(lid, j + 3);
                    float4 v0 = base4[(long)i0 * rowq + t];
                    float4 v1 = base4[(long)i1 * rowq + t];
                    float4 v2 = base4[(long)i2 * rowq + t];
                    float4 v3 = base4[(long)i3 * rowq + t];
                    acc.x += v0.x; acc.y += v0.y; acc.z += v0.z; acc.w += v0.w;
                    acc.x += v1.x; acc.y += v1.y; acc.z += v1.z; acc.w += v1.w;
                    acc.x += v2.x; acc.y += v2.y; acc.z += v2.z; acc.w += v2.w;
                    acc.x += v3.x; acc.y += v3.y; acc.z += v3.z; acc.w += v3.w;
                }
                for (; j < m; j++) {
                    int i0 = __shfl(lid, j);
                    float4 v0 = base4[(long)i0 * rowq + t];
                    acc.x += v0.x; acc.y += v0.y; acc.z += v0.z; acc.w += v0.w;
                }
            }
            float inv = 1.0f / (float)n;
            o0 = acc.x * inv; o1 = acc.y * inv; o2 = acc.z * inv; o3 = acc.w * inv;
        }
        float* dst = ftab + (long)c * D + t * 4;   // ftab only 8B-aligned -> scalar writes
        dst[0] = o0; dst[1] = o1; dst[2] = o2; dst[3] = o3;
        float ss = o0 * o0 + o1 * o1 + o2 * o2 + o3 * o3;
        ss = block_sum(ss, red);
        if (t == 0) norms[c] = sqrtf(ss);
    } else {
        // ---------------- logits path (W = C2 = 1000, lanes t<250 valid) ----------
        int c = blockIdx.x - C;
        int n = counts[c];
        int nv = C2 >> 2;                           // 250
        if (n == 0) {
            for (int d = t; d < C2; d += 256) ltab[(long)c * C2 + d] = linit[(long)c * C2 + d];
            return;
        }
        int tc = min(t, nv - 1);                    // clamped column -> unconditional loads
        int o = offsets[c];
        float4 acc = {0.f, 0.f, 0.f, 0.f};
        for (int base = 0; base < n; base += 64) {
            int m = min(64, n - base);
            int lid = idx[o + base + min(lane, m - 1)];
            int m4 = m & ~3;
            int j = 0;
            for (; j < m4; j += 4) {
                int i0 = __shfl(lid, j);
                int i1 = __shfl(lid, j + 1);
                int i2 = __shfl(lid, j + 2);
                int i3 = __shfl(lid, j + 3);
                float4 v0 = *(const float4*)(logits + (long)i0 * C2 + tc * 4);
                float4 v1 = *(const float4*)(logits + (long)i1 * C2 + tc * 4);
                float4 v2 = *(const float4*)(logits + (long)i2 * C2 + tc * 4);
                float4 v3 = *(const float4*)(logits + (long)i3 * C2 + tc * 4);
                acc.x += v0.x; acc.y += v0.y; acc.z += v0.z; acc.w += v0.w;
                acc.x += v1.x; acc.y += v1.y; acc.z += v1.z; acc.w += v1.w;
                acc.x += v2.x; acc.y += v2.y; acc.z += v2.z; acc.w += v2.w;
                acc.x += v3.x; acc.y += v3.y; acc.z += v3.z; acc.w += v3.w;
            }
            for (; j < m; j++) {
                int i0 = __shfl(lid, j);
                float4 v0 = *(const float4*)(logits + (long)i0 * C2 + tc * 4);
                acc.x += v0.x; acc.y += v0.y; acc.z += v0.z; acc.w += v0.w;
            }
        }
        if (t < nv) {
            float inv = 1.0f / (float)n;
            float* dst = ltab + (long)c * C2 + t * 4;  // 8B-aligned -> scalar writes
            dst[0] = acc.x * inv;
            dst[1] = acc.y * inv;
            dst[2] = acc.z * inv;
            dst[3] = acc.w * inv;
        }
    }
}

// Triangular raw-dot GEMM via bf16 MFMA: one block per upper-tri 64x64 tile,
// 1024 thr (16 waves, each owns one 16x16 output sub-tile), K-loop 32 steps of 32,
// double-buffered bf16 LDS, plain stores of S + mirror. No atomics.
__global__ __launch_bounds__(1024) void k_gemm(const float* A, float* S,
                                               int C, int D, int NT) {
    __shared__ __align__(16) unsigned short As[2][64][40];  // bf16, padded rows (80B)
    __shared__ __align__(16) unsigned short Bs[2][64][40];
    __shared__ __align__(16) float racc[64 * 68];
    int t = threadIdx.x;

    // decode triangular tile index
    int q = blockIdx.x, ti = 0;
    while (q >= NT - ti) { q -= NT - ti; ti++; }
    int tj = ti + q;
    int rb = ti * 64, cb = tj * 64;

    // staging: thread t -> row t>>4 (0..63), k-pair (t&15)*2 within 32-k step
    int srow = t >> 4;
    int skq = (t & 15) * 2;
    int ga = rb + srow, gb = cb + srow;
    bool okA = ga < C, okB = gb < C;
    const float* arow = A + (long)ga * D;
    const float* brow = A + (long)gb * D;

    // MFMA fragment indices: wave w -> sub-tile (wr,wc); lane l -> fr, fb, koff
    int w = t >> 6, wr = w >> 2, wc = w & 3;
    int l = t & 63, fr = l & 15, fb = l >> 4;
    int arl = wr * 16 + fr, brl = wc * 16 + fr, koff = fb * 8;

    // stage step 0
    {
        float2 z2 = {0.f, 0.f};
        float2 pa = okA ? *(const float2*)(arow + skq) : z2;
        float2 pb = okB ? *(const float2*)(brow + skq) : z2;
        As[0][srow][skq] = f2bf(pa.x); As[0][srow][skq + 1] = f2bf(pa.y);
        Bs[0][srow][skq] = f2bf(pb.x); Bs[0][srow][skq + 1] = f2bf(pb.y);
    }
    __syncthreads();

    f32x4 acc = {0.f, 0.f, 0.f, 0.f};
    int nsteps = D >> 5;               // 32
    for (int step = 0; step < nsteps; step++) {
        int cur = step & 1;
        float2 pa, pb;
        if (step < nsteps - 1) {
            int k0n = (step + 1) * 32;
            float2 z2 = {0.f, 0.f};
            pa = okA ? *(const float2*)(arow + k0n + skq) : z2;
            pb = okB ? *(const float2*)(brow + k0n + skq) : z2;
        }
        short8v af = *reinterpret_cast<const short8v*>(&As[cur][arl][koff]);
        short8v bf = *reinterpret_cast<const short8v*>(&Bs[cur][brl][koff]);
        acc = __builtin_amdgcn_mfma_f32_16x16x32_bf16(af, bf, acc, 0, 0, 0);
        if (step < nsteps - 1) {
            int nb = cur ^ 1;
            As[nb][srow][skq] = f2bf(pa.x); As[nb][srow][skq + 1] = f2bf(pa.y);
            Bs[nb][srow][skq] = f2bf(pb.x); Bs[nb][srow][skq + 1] = f2bf(pb.y);
        }
        __syncthreads();
    }

    // stage output tile into racc[row][col] (stride 68):
    // C/D layout: col = lane&15, row = (lane>>4)*4 + reg  (guide-verified)
#pragma unroll
    for (int r = 0; r < 4; r++)
        racc[(wr * 16 + fb * 4 + r) * 68 + wc * 16 + fr] = acc[r];
    __syncthreads();

    // cooperative stores: all 1024 threads, 4 cols each
    int r0 = t >> 4;                  // 0..63
    int cbl = (t & 15) * 4;           // local col base
    int gr = rb + r0;
    bool edge = (tj == NT - 1);
    if (gr < C) {
        float4 v4 = *reinterpret_cast<const float4*>(&racc[r0 * 68 + cbl]);
        float v[4] = {v4.x, v4.y, v4.z, v4.w};
        float* dst = S + (long)gr * C + cb + cbl;
        if (!edge) {
            *reinterpret_cast<float2*>(dst) = make_float2(v[0], v[1]);
            *reinterpret_cast<float2*>(dst + 2) = make_float2(v[2], v[3]);
        } else {
#pragma unroll
            for (int m = 0; m < 4; m++)
                if (cb + cbl + m < C) dst[m] = v[m];
        }
    }
    if (ti != tj) {
        int cc0 = cb + r0;
        if (cc0 < C) {
            float wv[4];
#pragma unroll
            for (int m = 0; m < 4; m++) wv[m] = racc[(cbl + m) * 68 + r0];
            float* dst = S + (long)cc0 * C + rb + cbl;
            *reinterpret_cast<float2*>(dst) = make_float2(wv[0], wv[1]);
            *reinterpret_cast<float2*>(dst + 2) = make_float2(wv[2], wv[3]);
        }
    }
}

// per-row: best/argmax (excl diag) of cos values + global min/max (incl diag).
__global__ void k_rowmax(const float* S, const float* norms, unsigned* minmax,
                         float* simraw, int* simcls, int C) {
    __shared__ float invn[1024];
    __shared__ float rv[256], rmn[256], rmx[256];
    __shared__ int ri[256];
    int c = blockIdx.x, t = threadIdx.x;
    for (int j = t; j < C; j += 256) invn[j] = 1.f / norms[j];
    __syncthreads();
    float inc = invn[c];
    float best = -INFINITY, lmin = INFINITY, lmax = -INFINITY;
    int bi = 0x7FFFFFFF;
    long rowo = (long)c * C;
    for (int j = t; j < C; j += 256) {
        float v = S[rowo + j] * inc * invn[j];
        lmin = fminf(lmin, v);
        lmax = fmaxf(lmax, v);
        if (j != c && v > best) { best = v; bi = j; }
    }
    rv[t] = best; ri[t] = bi; rmn[t] = lmin; rmx[t] = lmax;
    __syncthreads();
    for (int k = 128; k > 0; k >>= 1) {
        if (t < k) {
            if (rv[t + k] > rv[t] || (rv[t + k] == rv[t] && ri[t + k] < ri[t])) {
                rv[t] = rv[t + k];
                ri[t] = ri[t + k];
            }
            rmn[t] = fminf(rmn[t], rmn[t + k]);
            rmx[t] = fmaxf(rmx[t], rmx[t + k]);
        }
        __syncthreads();
    }
    if (t == 0) {
        simraw[c] = rv[0];
        simcls[c] = ri[0];
        atomicMin(&minmax[0], fenc(rmn[0]));
        atomicMax(&minmax[1], fenc(rmx[0]));
    }
}

// Fused losses: blocks [0, FB) do feature loss (wave per sample, 4/block);
// blocks [FB, 2*FB) do KL (wave per sample, 4/block). Independent paths.
__global__ __launch_bounds__(256) void k_losses(
        const float* feat, const float* ftab, const float* norms, const int* tgt,
        const unsigned* minmax, const float* simraw, const int* simcls,
        const float* logits, const float* LT,
        float* fpart, float* klpart, int B, int D, int C, int FB) {
    int wid = threadIdx.x >> 6, lane = threadIdx.x & 63;
    if ((int)blockIdx.x < FB) {
        int s = blockIdx.x * 4 + wid;
        int cls = tgt[s];
        int sc = simcls[cls];
        const float4* f4 = (const float4*)(feat + (long)s * D);
        const float2* ft2 = (const float2*)(ftab + (long)cls * D);
        const float2* fs2 = (const float2*)(ftab + (long)sc * D);
        float d1 = 0.f, d2 = 0.f, nf2 = 0.f;
#pragma unroll
        for (int i = 0; i < 4; i++) {
            int j = lane + i * 64;
            float4 x = f4[j];
            float2 a0 = ft2[2 * j], a1 = ft2[2 * j + 1];
            float2 b0 = fs2[2 * j], b1 = fs2[2 * j + 1];
            d1 += x.x * a0.x + x.y * a0.y + x.z * a1.x + x.w * a1.y;
            d2 += x.x * b0.x + x.y * b0.y + x.z * b1.x + x.w * b1.y;
            nf2 += x.x * x.x + x.y * x.y + x.z * x.z + x.w * x.w;
        }
        for (int o = 32; o > 0; o >>= 1) {
            d1 += __shfl_down(d1, o);
            d2 += __shfl_down(d2, o);
            nf2 += __shfl_down(nf2, o);
        }
        __shared__ float part[4];
        if (lane == 0) {
            float cmin = fdec(minmax[0]);
            float cmax = fdec(minmax[1]);
            float sv = (simraw[cls] - cmin) / (cmax - cmin);
            float nf = fmaxf(sqrtf(nf2), EPS);
            float nt = fmaxf(norms[cls], EPS);
            float ns = fmaxf(norms[sc], EPS);
            part[wid] = (1.f - d1 / (nf * nt)) + (d2 / (nf * ns)) * sv;
        }
        __syncthreads();
        if (threadIdx.x == 0) fpart[blockIdx.x] = part[0] + part[1] + part[2] + part[3];
    } else {
        int s = (blockIdx.x - FB) * 4 + wid;
        int cls = tgt[s];
        const float2* a2 = (const float2*)(LT + (long)cls * C);
        const float4* b4 = (const float4*)(logits + (long)s * C);
        int Q = C >> 2;   // 250
        float ta[16], tb[16];
        float m1 = -INFINITY, m2 = -INFINITY;
#pragma unroll
        for (int p = 0; p < 4; p++) {
            int j = lane + (p << 6);
            if (j < Q) {
                float4 vb = b4[j];
                float2 va0 = a2[2 * j], va1 = a2[2 * j + 1];
                ta[4 * p] = va0.x; ta[4 * p + 1] = va0.y;
                ta[4 * p + 2] = va1.x; ta[4 * p + 3] = va1.y;
                tb[4 * p] = vb.x; tb[4 * p + 1] = vb.y;
                tb[4 * p + 2] = vb.z; tb[4 * p + 3] = vb.w;
                m1 = fmaxf(m1, fmaxf(fmaxf(va0.x, va0.y), fmaxf(va1.x, va1.y)));
                m2 = fmaxf(m2, fmaxf(fmaxf(vb.x, vb.y), fmaxf(vb.z, vb.w)));
            } else {
#pragma unroll
                for (int r = 0; r < 4; r++) { ta[4 * p + r] = -INFINITY; tb[4 * p + r] = -INFINITY; }
            }
        }
#pragma unroll
        for (int o = 32; o > 0; o >>= 1) {
            m1 = fmaxf(m1, __shfl_xor(m1, o));
            m2 = fmaxf(m2, __shfl_xor(m2, o));
        }
        float e1[16];
        float s1 = 0.f, s2 = 0.f;
#pragma unroll
        for (int i = 0; i < 16; i++) {
            int j = lane + ((i >> 2) << 6);
            if (j < Q) {
                e1[i] = __expf(ta[i] - m1);
                s1 += e1[i];
                s2 += __expf(tb[i] - m2);
            } else {
                e1[i] = 0.f;
            }
        }
#pragma unroll
        for (int o = 32; o > 0; o >>= 1) {
            s1 += __shfl_xor(s1, o);
            s2 += __shfl_xor(s2, o);
        }
        float ls1 = __logf(s1), ls2 = __logf(s2);
        float inv = 1.f / s1;
        float kl = 0.f;
#pragma unroll
        for (int i = 0; i < 16; i++) {
            int j = lane + ((i >> 2) << 6);
            if (j < Q) {
                float lp = ta[i] - m1 - ls1;
                float lq = tb[i] - m2 - ls2;
                kl += e1[i] * inv * (lp - lq);
            }
        }
#pragma unroll
        for (int o = 32; o > 0; o >>= 1) kl += __shfl_xor(kl, o);
        if (lane == 0) klpart[s] = kl;
    }
}

__global__ void k_final(const float* fpart, const float* klpart, float* out, int nf, int nk) {
    __shared__ float red[256];
    float a = 0.f;
    for (int i = threadIdx.x; i < nf; i += 256) a += fpart[i];
    a = block_sum(a, red);
    float b = 0.f;
    for (int i = threadIdx.x; i < nk; i += 256) b += klpart[i];
    b = block_sum(b, red);
    if (threadIdx.x == 0) {
        out[0] = a;
        out[1] = b;
    }
}

extern "C" void kernel_launch(void* const* d_in, const int* in_sizes, int n_in,
                              void* d_out, int out_size, void* d_ws, size_t ws_size,
                              hipStream_t stream) {
    const float* feature = (const float*)d_in[0];
    const float* logits  = (const float*)d_in[1];
    const int*   targets = (const int*)d_in[2];
    const float* finit   = (const float*)d_in[3];
    const float* linit   = (const float*)d_in[4];

    const int B = in_sizes[2];                 // 16384
    const int D = in_sizes[0] / B;             // 1024
    const int C = in_sizes[3] / D;             // 1000

    float* out = (float*)d_out;
    float* ftab = out + 2;                     // [C, D]
    float* ltab = out + 2 + (long)C * D;       // [C, C]

    const int G = (B + 255) / 256;             // 64 groups
    const int NT = (C + 63) / 64;              // 16 tiles per dim
    const int NTRI = NT * (NT + 1) / 2;        // 136 triangular tiles

    char* ws = (char*)d_ws;
    int*      counts  = (int*)(ws + 0);        // 1024
    int*      offsets = (int*)(ws + 4096);     // 1024
    int*      idx     = (int*)(ws + 12288);    // 16384
    float*    norms   = (float*)(ws + 77824);  // 1024
    float*    simraw  = (float*)(ws + 81920);  // 1024
    int*      simcls  = (int*)(ws + 86016);    // 1024
    unsigned* minmax  = (unsigned*)(ws + 90112); // 2
    float*    fpart   = (float*)(ws + 90368);  // 4096
    float*    klpart  = (float*)(ws + 106752); // 16384
    float*    Sws     = (float*)(ws + 262144); // C*C floats (S scratch)

    // S in ws (ws_size >= 12.25 MB proven in round 12)
    int sInWs = (ws_size >= 262144 + (size_t)C * C * sizeof(float)) ? 1 : 0;
    float* S = sInWs ? Sws : ltab;

    // gh scratch lives in the (not-yet-written) ltab output region: G*1024 ints = 256 KB
    int* gh = (int*)ltab;

    k_ghist<<<G, 256, 0, stream>>>(targets, gh, B);
    k_bases<<<1, 1024, 0, stream>>>(gh, counts, offsets, minmax, G, C);
    k_rank_scatter<<<G, 256, 0, stream>>>(targets, offsets, gh, idx, B);

    if (sInWs) {
        // both gathers together (pattern-wall aggregates), then fast MFMA GEMM
        k_tables<<<2 * C, 256, 0, stream>>>(feature, finit, logits, linit,
                                            counts, offsets, idx, ftab, ltab, norms, C, D, C);
        k_gemm<<<NTRI, 1024, 0, stream>>>(ftab, S, C, D, NT);
        k_rowmax<<<C, 256, 0, stream>>>(S, norms, minmax, simraw, simcls, C);
    } else {
        // fallback: S lives in ltab region; ltab built after rowmax
        k_tables<<<C, 256, 0, stream>>>(feature, finit, logits, linit,
                                        counts, offsets, idx, ftab, ltab, norms, C, D, C);
        k_gemm<<<NTRI, 1024, 0, stream>>>(ftab, S, C, D, NT);
        k_rowmax<<<C, 256, 0, stream>>>(S, norms, minmax, simraw, simcls, C);
        k_tables<<<2 * C, 256, 0, stream>>>(feature, finit, logits, linit,
                                            counts, offsets, idx, ftab, ltab, norms, C, D, C);
    }

    const int FB = B / 4;
    k_losses<<<2 * FB, 256, 0, stream>>>(feature, ftab, norms, targets, minmax, simraw,
                                         simcls, logits, ltab, fpart, klpart, B, D, C, FB);
    k_final<<<1, 256, 0, stream>>>(fpart, klpart, out, FB, B);
}

// Round 25
// 154.789 us; speedup vs baseline: 1.0380x; 1.0380x over previous
//
#include <hip/hip_runtime.h>
#include <hip/hip_bf16.h>
#include <math.h>

#define EPS 1e-8f

typedef __attribute__((ext_vector_type(8))) short short8v;
typedef __attribute__((ext_vector_type(4))) float f32x4;

// ---------- helpers ----------
__device__ __forceinline__ unsigned fenc(float f) {
    unsigned u = __float_as_uint(f);
    return (u & 0x80000000u) ? ~u : (u | 0x80000000u);
}
__device__ __forceinline__ float fdec(unsigned e) {
    unsigned u = (e & 0x80000000u) ? (e & 0x7FFFFFFFu) : ~e;
    return __uint_as_float(u);
}
__device__ __forceinline__ unsigned short f2bf(float f) {   // RNE f32 -> bf16
    unsigned u = __float_as_uint(f);
    u += 0x7FFFu + ((u >> 16) & 1u);
    return (unsigned short)(u >> 16);
}

__device__ __forceinline__ float block_sum(float v, float* red) {
    red[threadIdx.x] = v;
    __syncthreads();
    for (int k = 128; k > 0; k >>= 1) {
        if (threadIdx.x < k) red[threadIdx.x] += red[threadIdx.x + k];
        __syncthreads();
    }
    float r = red[0];
    __syncthreads();
    return r;
}

// ---------- kernels ----------
__global__ void k_ghist(const int* tgt, int* gh, int B) {
    __shared__ int lh[1024];
    int g = blockIdx.x, t = threadIdx.x;
    lh[t] = 0; lh[t + 256] = 0; lh[t + 512] = 0; lh[t + 768] = 0;
    __syncthreads();
    int i = g * 256 + t;
    if (i < B) atomicAdd(&lh[tgt[i]], 1);
    __syncthreads();
    int* dst = gh + g * 1024;
    dst[t] = lh[t]; dst[t + 256] = lh[t + 256];
    dst[t + 512] = lh[t + 512]; dst[t + 768] = lh[t + 768];
}

__global__ void k_bases(int* gh, int* counts, int* offsets, unsigned* minmax, int G, int C) {
    __shared__ int buf[1024];
    int c = threadIdx.x;
    if (c == 0) { minmax[0] = 0xFFFFFFFFu; minmax[1] = 0u; }
    int run = 0;
#pragma unroll 16
    for (int g = 0; g < G; g++) {
        int v = gh[g * 1024 + c];
        gh[g * 1024 + c] = run;
        run += v;
    }
    if (c < C) counts[c] = run;
    int v0 = (c < C) ? run : 0;
    buf[c] = v0;
    __syncthreads();
    for (int off = 1; off < 1024; off <<= 1) {
        int v = (c >= off) ? buf[c - off] : 0;
        __syncthreads();
        buf[c] += v;
        __syncthreads();
    }
    if (c < C) offsets[c] = buf[c] - v0;
}

__global__ void k_rank_scatter(const int* tgt, const int* offsets, const int* gh,
                               int* idx, int B) {
    __shared__ int lt[256];
    int g = blockIdx.x, t = threadIdx.x;
    int i = g * 256 + t;
    int my = (i < B) ? tgt[i] : -1;
    lt[t] = my;
    __syncthreads();
    if (i < B) {
        int rank = 0;
        for (int j = 0; j < t; j++) rank += (lt[j] == my);
        idx[offsets[my] + gh[g * 1024 + my] + rank] = i;
    }
}

// feature table + norms: one 256-thr block per class (register idx + __shfl).
__global__ __launch_bounds__(256) void k_ftab(const float* feat, const float* finit,
                                              const int* counts, const int* offsets,
                                              const int* idx, float* ftab, float* norms,
                                              int C, int D) {
    __shared__ float red[256];
    int t = threadIdx.x;
    int lane = t & 63;
    int c = blockIdx.x;
    int n = counts[c];
    float o0, o1, o2, o3;
    if (n == 0) {
        float4 v = ((const float4*)(finit + (long)c * D))[t];
        o0 = v.x; o1 = v.y; o2 = v.z; o3 = v.w;
    } else {
        const float4* base4 = (const float4*)feat;
        int rowq = D >> 2;
        int o = offsets[c];
        float4 acc = {0.f, 0.f, 0.f, 0.f};
        for (int base = 0; base < n; base += 64) {
            int m = min(64, n - base);
            int lid = idx[o + base + min(lane, m - 1)];
            int m4 = m & ~3;
            int j = 0;
            for (; j < m4; j += 4) {
                int i0 = __shfl(lid, j);
                int i1 = __shfl(lid, j + 1);
                int i2 = __shfl(lid, j + 2);
                int i3 = __shfl(lid, j + 3);
                float4 v0 = base4[(long)i0 * rowq + t];
                float4 v1 = base4[(long)i1 * rowq + t];
                float4 v2 = base4[(long)i2 * rowq + t];
                float4 v3 = base4[(long)i3 * rowq + t];
                acc.x += v0.x; acc.y += v0.y; acc.z += v0.z; acc.w += v0.w;
                acc.x += v1.x; acc.y += v1.y; acc.z += v1.z; acc.w += v1.w;
                acc.x += v2.x; acc.y += v2.y; acc.z += v2.z; acc.w += v2.w;
                acc.x += v3.x; acc.y += v3.y; acc.z += v3.z; acc.w += v3.w;
            }
            for (; j < m; j++) {
                int i0 = __shfl(lid, j);
                float4 v0 = base4[(long)i0 * rowq + t];
                acc.x += v0.x; acc.y += v0.y; acc.z += v0.z; acc.w += v0.w;
            }
        }
        float inv = 1.0f / (float)n;
        o0 = acc.x * inv; o1 = acc.y * inv; o2 = acc.z * inv; o3 = acc.w * inv;
    }
    float* dst = ftab + (long)c * D + t * 4;
    dst[0] = o0; dst[1] = o1; dst[2] = o2; dst[3] = o3;
    float ss = o0 * o0 + o1 * o1 + o2 * o2 + o3 * o3;
    ss = block_sum(ss, red);
    if (t == 0) norms[c] = sqrtf(ss);
}

// FUSED: blocks [0,NTRI) = bf16-MFMA triangular GEMM tile; blocks [NTRI,..) =
// ltab gather (4 classes/block). Gather backfills the CUs the GEMM leaves idle.
__global__ __launch_bounds__(1024) void k_gemm_ltab(const float* A, float* S,
                                                    const float* logits, const float* linit,
                                                    const int* counts, const int* offsets,
                                                    const int* idx, float* ltab,
                                                    int C, int D, int NT, int NTRI, int C2) {
    __shared__ __align__(16) unsigned short As[2][64][40];
    __shared__ __align__(16) unsigned short Bs[2][64][40];
    __shared__ __align__(16) float racc[64 * 68];
    int t = threadIdx.x;

    if ((int)blockIdx.x >= NTRI) {
        // ---------------- ltab gather path ----------------
        int q = t >> 8;
        int tq = t & 255;
        int lane = t & 63;
        int c = ((int)blockIdx.x - NTRI) * 4 + q;
        if (c >= C) return;
        int n = counts[c];
        int nv = C2 >> 2;               // 250
        if (n == 0) {
            for (int d = tq; d < C2; d += 256) ltab[(long)c * C2 + d] = linit[(long)c * C2 + d];
            return;
        }
        int tc = min(tq, nv - 1);
        int o = offsets[c];
        float4 acc = {0.f, 0.f, 0.f, 0.f};
        for (int base = 0; base < n; base += 64) {
            int m = min(64, n - base);
            int lid = idx[o + base + min(lane, m - 1)];
            int m4 = m & ~3;
            int j = 0;
            for (; j < m4; j += 4) {
                int i0 = __shfl(lid, j);
                int i1 = __shfl(lid, j + 1);
                int i2 = __shfl(lid, j + 2);
                int i3 = __shfl(lid, j + 3);
                float4 v0 = *(const float4*)(logits + (long)i0 * C2 + tc * 4);
                float4 v1 = *(const float4*)(logits + (long)i1 * C2 + tc * 4);
                float4 v2 = *(const float4*)(logits + (long)i2 * C2 + tc * 4);
                float4 v3 = *(const float4*)(logits + (long)i3 * C2 + tc * 4);
                acc.x += v0.x; acc.y += v0.y; acc.z += v0.z; acc.w += v0.w;
                acc.x += v1.x; acc.y += v1.y; acc.z += v1.z; acc.w += v1.w;
                acc.x += v2.x; acc.y += v2.y; acc.z += v2.z; acc.w += v2.w;
                acc.x += v3.x; acc.y += v3.y; acc.z += v3.z; acc.w += v3.w;
            }
            for (; j < m; j++) {
                int i0 = __shfl(lid, j);
                float4 v0 = *(const float4*)(logits + (long)i0 * C2 + tc * 4);
                acc.x += v0.x; acc.y += v0.y; acc.z += v0.z; acc.w += v0.w;
            }
        }
        if (tq < nv) {
            float inv = 1.0f / (float)n;
            float* dst = ltab + (long)c * C2 + tq * 4;
            dst[0] = acc.x * inv;
            dst[1] = acc.y * inv;
            dst[2] = acc.z * inv;
            dst[3] = acc.w * inv;
        }
        return;
    }

    // ---------------- GEMM tile path (bf16 MFMA) ----------------
    int q = blockIdx.x, ti = 0;
    while (q >= NT - ti) { q -= NT - ti; ti++; }
    int tj = ti + q;
    int rb = ti * 64, cb = tj * 64;

    int srow = t >> 4;
    int skq = (t & 15) * 2;
    int ga = rb + srow, gb = cb + srow;
    bool okA = ga < C, okB = gb < C;
    const float* arow = A + (long)ga * D;
    const float* brow = A + (long)gb * D;

    int w = t >> 6, wr = w >> 2, wc = w & 3;
    int l = t & 63, fr = l & 15, fb = l >> 4;
    int arl = wr * 16 + fr, brl = wc * 16 + fr, koff = fb * 8;

    {
        float2 z2 = {0.f, 0.f};
        float2 pa = okA ? *(const float2*)(arow + skq) : z2;
        float2 pb = okB ? *(const float2*)(brow + skq) : z2;
        As[0][srow][skq] = f2bf(pa.x); As[0][srow][skq + 1] = f2bf(pa.y);
        Bs[0][srow][skq] = f2bf(pb.x); Bs[0][srow][skq + 1] = f2bf(pb.y);
    }
    __syncthreads();

    f32x4 acc = {0.f, 0.f, 0.f, 0.f};
    int nsteps = D >> 5;               // 32
    for (int step = 0; step < nsteps; step++) {
        int cur = step & 1;
        float2 pa, pb;
        if (step < nsteps - 1) {
            int k0n = (step + 1) * 32;
            float2 z2 = {0.f, 0.f};
            pa = okA ? *(const float2*)(arow + k0n + skq) : z2;
            pb = okB ? *(const float2*)(brow + k0n + skq) : z2;
        }
        short8v af = *reinterpret_cast<const short8v*>(&As[cur][arl][koff]);
        short8v bf = *reinterpret_cast<const short8v*>(&Bs[cur][brl][koff]);
        acc = __builtin_amdgcn_mfma_f32_16x16x32_bf16(af, bf, acc, 0, 0, 0);
        if (step < nsteps - 1) {
            int nb = cur ^ 1;
            As[nb][srow][skq] = f2bf(pa.x); As[nb][srow][skq + 1] = f2bf(pa.y);
            Bs[nb][srow][skq] = f2bf(pb.x); Bs[nb][srow][skq + 1] = f2bf(pb.y);
        }
        __syncthreads();
    }

#pragma unroll
    for (int r = 0; r < 4; r++)
        racc[(wr * 16 + fb * 4 + r) * 68 + wc * 16 + fr] = acc[r];
    __syncthreads();

    int r0 = t >> 4;
    int cbl = (t & 15) * 4;
    int gr = rb + r0;
    bool edge = (tj == NT - 1);
    if (gr < C) {
        float4 v4 = *reinterpret_cast<const float4*>(&racc[r0 * 68 + cbl]);
        float v[4] = {v4.x, v4.y, v4.z, v4.w};
        float* dst = S + (long)gr * C + cb + cbl;
        if (!edge) {
            *reinterpret_cast<float2*>(dst) = make_float2(v[0], v[1]);
            *reinterpret_cast<float2*>(dst + 2) = make_float2(v[2], v[3]);
        } else {
#pragma unroll
            for (int m = 0; m < 4; m++)
                if (cb + cbl + m < C) dst[m] = v[m];
        }
    }
    if (ti != tj) {
        int cc0 = cb + r0;
        if (cc0 < C) {
            float wv[4];
#pragma unroll
            for (int m = 0; m < 4; m++) wv[m] = racc[(cbl + m) * 68 + r0];
            float* dst = S + (long)cc0 * C + rb + cbl;
            *reinterpret_cast<float2*>(dst) = make_float2(wv[0], wv[1]);
            *reinterpret_cast<float2*>(dst + 2) = make_float2(wv[2], wv[3]);
        }
    }
}

// FUSED: blocks [0,NR) = per-row max/argmax + global min/max on S;
// blocks [NR, NR+KB) = KL losses (wave per sample, 4/block). KL needs only ltab.
__global__ __launch_bounds__(256) void k_rowkl(const float* S, const float* norms,
                                               unsigned* minmax, float* simraw, int* simcls,
                                               const float* logits, const float* LT,
                                               const int* tgt, float* klpart,
                                               int C, int NR) {
    int t = threadIdx.x;
    if ((int)blockIdx.x < NR) {
        // ---------------- rowmax path ----------------
        __shared__ float invn[1024];
        __shared__ float rv[256], rmn[256], rmx[256];
        __shared__ int ri[256];
        int c = blockIdx.x;
        for (int j = t; j < C; j += 256) invn[j] = 1.f / norms[j];
        __syncthreads();
        float inc = invn[c];
        float best = -INFINITY, lmin = INFINITY, lmax = -INFINITY;
        int bi = 0x7FFFFFFF;
        long rowo = (long)c * C;
        for (int j = t; j < C; j += 256) {
            float v = S[rowo + j] * inc * invn[j];
            lmin = fminf(lmin, v);
            lmax = fmaxf(lmax, v);
            if (j != c && v > best) { best = v; bi = j; }
        }
        rv[t] = best; ri[t] = bi; rmn[t] = lmin; rmx[t] = lmax;
        __syncthreads();
        for (int k = 128; k > 0; k >>= 1) {
            if (t < k) {
                if (rv[t + k] > rv[t] || (rv[t + k] == rv[t] && ri[t + k] < ri[t])) {
                    rv[t] = rv[t + k];
                    ri[t] = ri[t + k];
                }
                rmn[t] = fminf(rmn[t], rmn[t + k]);
                rmx[t] = fmaxf(rmx[t], rmx[t + k]);
            }
            __syncthreads();
        }
        if (t == 0) {
            simraw[c] = rv[0];
            simcls[c] = ri[0];
            atomicMin(&minmax[0], fenc(rmn[0]));
            atomicMax(&minmax[1], fenc(rmx[0]));
        }
    } else {
        // ---------------- KL path ----------------
        int wid = t >> 6, lane = t & 63;
        int s = ((int)blockIdx.x - NR) * 4 + wid;
        int cls = tgt[s];
        const float2* a2 = (const float2*)(LT + (long)cls * C);      // 8B-aligned
        const float4* b4 = (const float4*)(logits + (long)s * C);    // 16B-aligned
        int Q = C >> 2;   // 250
        float ta[16], tb[16];
        float m1 = -INFINITY, m2 = -INFINITY;
#pragma unroll
        for (int p = 0; p < 4; p++) {
            int j = lane + (p << 6);
            if (j < Q) {
                float4 vb = b4[j];
                float2 va0 = a2[2 * j], va1 = a2[2 * j + 1];
                ta[4 * p] = va0.x; ta[4 * p + 1] = va0.y;
                ta[4 * p + 2] = va1.x; ta[4 * p + 3] = va1.y;
                tb[4 * p] = vb.x; tb[4 * p + 1] = vb.y;
                tb[4 * p + 2] = vb.z; tb[4 * p + 3] = vb.w;
                m1 = fmaxf(m1, fmaxf(fmaxf(va0.x, va0.y), fmaxf(va1.x, va1.y)));
                m2 = fmaxf(m2, fmaxf(fmaxf(vb.x, vb.y), fmaxf(vb.z, vb.w)));
            } else {
#pragma unroll
                for (int r = 0; r < 4; r++) { ta[4 * p + r] = -INFINITY; tb[4 * p + r] = -INFINITY; }
            }
        }
#pragma unroll
        for (int o = 32; o > 0; o >>= 1) {
            m1 = fmaxf(m1, __shfl_xor(m1, o));
            m2 = fmaxf(m2, __shfl_xor(m2, o));
        }
        float e1[16];
        float s1 = 0.f, s2 = 0.f;
#pragma unroll
        for (int i = 0; i < 16; i++) {
            int j = lane + ((i >> 2) << 6);
            if (j < Q) {
                e1[i] = __expf(ta[i] - m1);
                s1 += e1[i];
                s2 += __expf(tb[i] - m2);
            } else {
                e1[i] = 0.f;
            }
        }
#pragma unroll
        for (int o = 32; o > 0; o >>= 1) {
            s1 += __shfl_xor(s1, o);
            s2 += __shfl_xor(s2, o);
        }
        float ls1 = __logf(s1), ls2 = __logf(s2);
        float inv = 1.f / s1;
        float kl = 0.f;
#pragma unroll
        for (int i = 0; i < 16; i++) {
            int j = lane + ((i >> 2) << 6);
            if (j < Q) {
                float lp = ta[i] - m1 - ls1;
                float lq = tb[i] - m2 - ls2;
                kl += e1[i] * inv * (lp - lq);
            }
        }
#pragma unroll
        for (int o = 32; o > 0; o >>= 1) kl += __shfl_xor(kl, o);
        if (lane == 0) klpart[s] = kl;
    }
}

// feature loss: wave per sample, 4 samples/block.
__global__ __launch_bounds__(256) void k_floss(
        const float* feat, const float* ftab, const float* norms, const int* tgt,
        const unsigned* minmax, const float* simraw, const int* simcls,
        float* fpart, int B, int D) {
    int wid = threadIdx.x >> 6, lane = threadIdx.x & 63;
    int s = blockIdx.x * 4 + wid;
    int cls = tgt[s];
    int sc = simcls[cls];
    const float4* f4 = (const float4*)(feat + (long)s * D);
    const float2* ft2 = (const float2*)(ftab + (long)cls * D);
    const float2* fs2 = (const float2*)(ftab + (long)sc * D);
    float d1 = 0.f, d2 = 0.f, nf2 = 0.f;
#pragma unroll
    for (int i = 0; i < 4; i++) {
        int j = lane + i * 64;
        float4 x = f4[j];
        float2 a0 = ft2[2 * j], a1 = ft2[2 * j + 1];
        float2 b0 = fs2[2 * j], b1 = fs2[2 * j + 1];
        d1 += x.x * a0.x + x.y * a0.y + x.z * a1.x + x.w * a1.y;
        d2 += x.x * b0.x + x.y * b0.y + x.z * b1.x + x.w * b1.y;
        nf2 += x.x * x.x + x.y * x.y + x.z * x.z + x.w * x.w;
    }
    for (int o = 32; o > 0; o >>= 1) {
        d1 += __shfl_down(d1, o);
        d2 += __shfl_down(d2, o);
        nf2 += __shfl_down(nf2, o);
    }
    __shared__ float part[4];
    if (lane == 0) {
        float cmin = fdec(minmax[0]);
        float cmax = fdec(minmax[1]);
        float sv = (simraw[cls] - cmin) / (cmax - cmin);
        float nf = fmaxf(sqrtf(nf2), EPS);
        float nt = fmaxf(norms[cls], EPS);
        float ns = fmaxf(norms[sc], EPS);
        part[wid] = (1.f - d1 / (nf * nt)) + (d2 / (nf * ns)) * sv;
    }
    __syncthreads();
    if (threadIdx.x == 0) fpart[blockIdx.x] = part[0] + part[1] + part[2] + part[3];
}

__global__ void k_final(const float* fpart, const float* klpart, float* out, int nf, int nk) {
    __shared__ float red[256];
    float a = 0.f;
    for (int i = threadIdx.x; i < nf; i += 256) a += fpart[i];
    a = block_sum(a, red);
    float b = 0.f;
    for (int i = threadIdx.x; i < nk; i += 256) b += klpart[i];
    b = block_sum(b, red);
    if (threadIdx.x == 0) {
        out[0] = a;
        out[1] = b;
    }
}

extern "C" void kernel_launch(void* const* d_in, const int* in_sizes, int n_in,
                              void* d_out, int out_size, void* d_ws, size_t ws_size,
                              hipStream_t stream) {
    const float* feature = (const float*)d_in[0];
    const float* logits  = (const float*)d_in[1];
    const int*   targets = (const int*)d_in[2];
    const float* finit   = (const float*)d_in[3];
    const float* linit   = (const float*)d_in[4];

    const int B = in_sizes[2];                 // 16384
    const int D = in_sizes[0] / B;             // 1024
    const int C = in_sizes[3] / D;             // 1000

    float* out = (float*)d_out;
    float* ftab = out + 2;                     // [C, D]
    float* ltab = out + 2 + (long)C * D;       // [C, C]

    const int G = (B + 255) / 256;             // 64 groups
    const int NT = (C + 63) / 64;              // 16 tiles per dim
    const int NTRI = NT * (NT + 1) / 2;        // 136 triangular tiles
    const int NG4 = (C + 3) / 4;               // 250 ltab-gather blocks

    char* ws = (char*)d_ws;
    int*      counts  = (int*)(ws + 0);        // 1024
    int*      offsets = (int*)(ws + 4096);     // 1024
    int*      idx     = (int*)(ws + 12288);    // 16384
    float*    norms   = (float*)(ws + 77824);  // 1024
    float*    simraw  = (float*)(ws + 81920);  // 1024
    int*      simcls  = (int*)(ws + 86016);    // 1024
    unsigned* minmax  = (unsigned*)(ws + 90112); // 2
    float*    fpart   = (float*)(ws + 90368);  // 4096
    float*    klpart  = (float*)(ws + 106752); // 16384
    float*    Sws     = (float*)(ws + 262144); // C*C floats (S scratch)

    int sInWs = (ws_size >= 262144 + (size_t)C * C * sizeof(float)) ? 1 : 0;
    float* S = sInWs ? Sws : ltab;

    // gh scratch lives in the (not-yet-written) ltab output region
    int* gh = (int*)ltab;

    k_ghist<<<G, 256, 0, stream>>>(targets, gh, B);
    k_bases<<<1, 1024, 0, stream>>>(gh, counts, offsets, minmax, G, C);
    k_rank_scatter<<<G, 256, 0, stream>>>(targets, offsets, gh, idx, B);

    k_ftab<<<C, 256, 0, stream>>>(feature, finit, counts, offsets, idx, ftab, norms, C, D);

    const int KB = B / 4;
    if (sInWs) {
        // GEMM tiles + ltab gather fused; then rowmax fused with KL losses.
        k_gemm_ltab<<<NTRI + NG4, 1024, 0, stream>>>(ftab, S, logits, linit,
                                                     counts, offsets, idx, ltab,
                                                     C, D, NT, NTRI, C);
        k_rowkl<<<C + KB, 256, 0, stream>>>(S, norms, minmax, simraw, simcls,
                                            logits, ltab, targets, klpart, C, C);
    } else {
        // fallback: S in ltab region; ltab built after rowmax; KL after ltab.
        k_gemm_ltab<<<NTRI, 1024, 0, stream>>>(ftab, S, logits, linit,
                                               counts, offsets, idx, ltab,
                                               C, D, NT, NTRI, C);
        k_rowkl<<<C, 256, 0, stream>>>(S, norms, minmax, simraw, simcls,
                                       logits, ltab, targets, klpart, C, C);
        k_gemm_ltab<<<dim3(NG4), 1024, 0, stream>>>(ftab, S, logits, linit,
                                                    counts, offsets, idx, ltab,
                                                    C, D, NT, 0 /*all gather*/, C);
        k_rowkl<<<KB, 256, 0, stream>>>(S, norms, minmax, simraw, simcls,
                                        logits, ltab, targets, klpart, C, 0 /*KL only*/);
    }

    k_floss<<<B / 4, 256, 0, stream>>>(feature, ftab, norms, targets, minmax, simraw,
                                       simcls, fpart, B, D);
    k_final<<<1, 256, 0, stream>>>(fpart, klpart, out, B / 4, B);
}